// Round 1
// baseline (598.570 us; speedup 1.0000x reference)
//
#include <hip/hip_runtime.h>

// Problem constants (GRID=192, ISO=0)
#define GN 192           // grid points per axis
#define CN 193           // cells per axis (GN+1)

// Output layout (float32 elements), in reference return order:
//   verts : CN^3 * 3
//   vmask : CN^3
//   quads : 3 * CN*GN*GN * 4
//   qmask : 3 * CN*GN*GN
#define NV        ((size_t)CN * CN * CN)                  // 7,189,057
#define OFF_VMASK ((size_t)(NV * 3))                      // 21,567,171
#define OFF_QUADS ((size_t)(OFF_VMASK + NV))              // 28,756,228
#define QSEG      ((size_t)CN * GN * GN)                  // 7,114,752 rows per segment
#define OFF_QMASK ((size_t)(OFF_QUADS + 3 * QSEG * 4))    // 114,133,252

// Load grid value for PADDED coordinate (x,y,z) in [0, GN+2); pad value = iso+1 = 1.0f.
// Padded coord p maps to grid index p-1 (valid when 1 <= p <= GN).
__device__ __forceinline__ float gpad(const float* __restrict__ g, int x, int y, int z) {
    // x,y,z here are already grid-space (padded - 1): valid iff in [0, GN)
    if ((unsigned)x < (unsigned)GN && (unsigned)y < (unsigned)GN && (unsigned)z < (unsigned)GN)
        return g[((size_t)x * GN + y) * GN + z];
    return 1.0f;
}

// sign bit of padded grid: (P < iso). Pad value 1.0 -> false.
__device__ __forceinline__ bool spad(const float* __restrict__ g, int px, int py, int pz) {
    int x = px - 1, y = py - 1, z = pz - 1;
    if ((unsigned)x < (unsigned)GN && (unsigned)y < (unsigned)GN && (unsigned)z < (unsigned)GN)
        return g[((size_t)x * GN + y) * GN + z] < 0.0f;
    return false;
}

__device__ __forceinline__ float fcid(int a, int b, int c) {
    return (float)((a * CN + b) * CN + c);   // max 7,189,056 < 2^24 : exact in f32
}

// --------------------------- dual vertices --------------------------------
// One thread per cell (i,j,k) in [0,CN)^3. block=(256,1,1): k=threadIdx.x,
// j=blockIdx.y, i=blockIdx.z.
__global__ __launch_bounds__(256) void verts_kernel(const float* __restrict__ g,
                                                    float* __restrict__ out) {
    const int k = threadIdx.x;
    const int j = blockIdx.y;
    const int i = blockIdx.z;
    if (k >= CN) return;

    // 8 corner values of padded cell: P[i+di][j+dj][k+dk] = grid[i-1+di][...]
    const float v000 = gpad(g, i - 1, j - 1, k - 1);
    const float v100 = gpad(g, i,     j - 1, k - 1);
    const float v010 = gpad(g, i - 1, j,     k - 1);
    const float v110 = gpad(g, i,     j,     k - 1);
    const float v001 = gpad(g, i - 1, j - 1, k);
    const float v101 = gpad(g, i,     j - 1, k);
    const float v011 = gpad(g, i - 1, j,     k);
    const float v111 = gpad(g, i,     j,     k);

    float sx = 0.f, sy = 0.f, sz = 0.f;
    int cnt = 0;

    // axis: 0 -> crossing point (t, o1, o2); 1 -> (o1, t, o2); 2 -> (o1, o2, t)
    auto acc = [&](float vA, float vB, int axis, float o1, float o2) {
        if ((vA < 0.f) != (vB < 0.f)) {
            float t = -vA / (vB - vA);
            if (axis == 0)      { sx += t;  sy += o1; sz += o2; }
            else if (axis == 1) { sx += o1; sy += t;  sz += o2; }
            else                { sx += o1; sy += o2; sz += t;  }
            cnt++;
        }
    };
    // x-directed edges
    acc(v000, v100, 0, 0.f, 0.f);
    acc(v010, v110, 0, 1.f, 0.f);
    acc(v001, v101, 0, 0.f, 1.f);
    acc(v011, v111, 0, 1.f, 1.f);
    // y-directed edges
    acc(v000, v010, 1, 0.f, 0.f);
    acc(v100, v110, 1, 1.f, 0.f);
    acc(v001, v011, 1, 0.f, 1.f);
    acc(v101, v111, 1, 1.f, 1.f);
    // z-directed edges
    acc(v000, v001, 2, 0.f, 0.f);
    acc(v100, v101, 2, 1.f, 0.f);
    acc(v010, v011, 2, 0.f, 1.f);
    acc(v110, v111, 2, 1.f, 1.f);

    const float cm = fmaxf((float)cnt, 1.0f);
    const float inv191 = 1.0f / 191.0f;   // (dim - 1)
    const float vx = ((float)i + sx / cm - 1.0f) * inv191;
    const float vy = ((float)j + sy / cm - 1.0f) * inv191;
    const float vz = ((float)k + sz / cm - 1.0f) * inv191;

    const size_t idx = ((size_t)i * CN + j) * CN + k;
    out[idx * 3 + 0] = vx;
    out[idx * 3 + 1] = vy;
    out[idx * 3 + 2] = vz;
    out[OFF_VMASK + idx] = (cnt > 0) ? 1.0f : 0.0f;
}

// ----------------------------- quads --------------------------------------
// Segment A: x-directed edges. a in [0,193), b in [1,193), c in [1,193).
// Row order: (a, b-1, c-1) with c fastest. inner = 192*192 = 36864 = 144*256.
__global__ __launch_bounds__(256) void quadsA(const float* __restrict__ g,
                                              float* __restrict__ out) {
    const int t = blockIdx.x * 256 + threadIdx.x;   // 0..36863, exact
    const int a = blockIdx.z;                       // 0..192
    const int bi = t / GN, ci = t % GN;             // b-1, c-1

    const bool m = spad(g, a, bi + 1, ci + 1) != spad(g, a + 1, bi + 1, ci + 1);
    const size_t r = ((size_t)a * GN + bi) * GN + ci;

    float4 q;
    q.x = fcid(a, bi,     ci);
    q.y = fcid(a, bi + 1, ci);
    q.z = fcid(a, bi + 1, ci + 1);
    q.w = fcid(a, bi,     ci + 1);
    ((float4*)(out + OFF_QUADS))[r] = q;
    out[OFF_QMASK + r] = m ? 1.0f : 0.0f;
}

// Segment B: y-directed edges. a in [1,193), b in [0,193), c in [1,193).
// Row order: (a-1, b, c-1), c fastest. inner = 193*192 = 37056 (needs bound check).
__global__ __launch_bounds__(256) void quadsB(const float* __restrict__ g,
                                              float* __restrict__ out) {
    const int t = blockIdx.x * 256 + threadIdx.x;
    if (t >= CN * GN) return;                       // 37056
    const int a = blockIdx.z + 1;                   // 1..192
    const int b = t / GN, ci = t % GN;              // b in 0..192, c-1 in 0..191

    const bool m = spad(g, a, b, ci + 1) != spad(g, a, b + 1, ci + 1);
    const size_t r = QSEG + ((size_t)(a - 1) * CN + b) * GN + ci;

    float4 q;
    q.x = fcid(a - 1, b, ci);
    q.y = fcid(a,     b, ci);
    q.z = fcid(a,     b, ci + 1);
    q.w = fcid(a - 1, b, ci + 1);
    ((float4*)(out + OFF_QUADS))[r] = q;
    out[OFF_QMASK + r] = m ? 1.0f : 0.0f;
}

// Segment C: z-directed edges. a in [1,193), b in [1,193), c in [0,193).
// Row order: (a-1, b-1, c), c fastest. inner = 192*193 = 37056.
__global__ __launch_bounds__(256) void quadsC(const float* __restrict__ g,
                                              float* __restrict__ out) {
    const int t = blockIdx.x * 256 + threadIdx.x;
    if (t >= GN * CN) return;                       // 37056
    const int a = blockIdx.z + 1;                   // 1..192
    const int bi = t / CN, c = t % CN;              // b-1 in 0..191, c in 0..192
    const int b = bi + 1;

    const bool m = spad(g, a, b, c) != spad(g, a, b, c + 1);
    const size_t r = 2 * QSEG + ((size_t)bi * CN + c) + (size_t)(a - 1) * GN * CN;

    float4 q;
    q.x = fcid(a - 1, b - 1, c);
    q.y = fcid(a,     b - 1, c);
    q.z = fcid(a,     b,     c);
    q.w = fcid(a - 1, b,     c);
    ((float4*)(out + OFF_QUADS))[r] = q;
    out[OFF_QMASK + r] = m ? 1.0f : 0.0f;
}

extern "C" void kernel_launch(void* const* d_in, const int* in_sizes, int n_in,
                              void* d_out, int out_size, void* d_ws, size_t ws_size,
                              hipStream_t stream) {
    const float* g = (const float*)d_in[0];
    float* out = (float*)d_out;

    // Dual vertices + vmask: one thread per cell, 193 active lanes of 256.
    verts_kernel<<<dim3(1, CN, CN), dim3(256), 0, stream>>>(g, out);

    // Quads + qmask, three edge directions.
    quadsA<<<dim3(144, 1, CN), dim3(256), 0, stream>>>(g, out);  // 144*256 = 36864 exact
    quadsB<<<dim3(145, 1, GN), dim3(256), 0, stream>>>(g, out);  // 145*256 >= 37056
    quadsC<<<dim3(145, 1, GN), dim3(256), 0, stream>>>(g, out);
}

// Round 2
// 557.293 us; speedup vs baseline: 1.0741x; 1.0741x over previous
//
#include <hip/hip_runtime.h>

// Problem constants (GRID=192, ISO=0)
#define GN 192           // grid points per axis
#define CN 193           // cells per axis (GN+1)
#define CN2 (CN * CN)    // 37249

// Output layout (float32 elements), in reference return order:
//   verts : CN^3 * 3
//   vmask : CN^3
//   quads : 3 * CN*GN*GN * 4
//   qmask : 3 * CN*GN*GN
#define NV        ((size_t)CN * CN * CN)                  // 7,189,057
#define OFF_VMASK ((size_t)(NV * 3))                      // 21,567,171
#define OFF_QUADS ((size_t)(OFF_VMASK + NV))              // 28,756,228
#define QSEG      ((size_t)CN * GN * GN)                  // 7,114,752 rows per segment
#define OFF_QMASK ((size_t)(OFF_QUADS + 3 * QSEG * 4))    // 114,133,252

// Load grid value for cell-corner coordinate in GRID space; OOB -> pad = iso+1 = 1.
__device__ __forceinline__ float gpad(const float* __restrict__ g, int x, int y, int z) {
    if ((unsigned)x < (unsigned)GN && (unsigned)y < (unsigned)GN && (unsigned)z < (unsigned)GN)
        return g[((size_t)x * GN + y) * GN + z];
    return 1.0f;
}

// ------------------------- fused DMC kernel -------------------------------
// One thread per cell lin = (i*193 + j)*193 + k. The 8 corner loads serve the
// dual-vertex placement AND all three quad-edge masks. Quad cell ids are
// lin +/- small constants (exact in f32, < 2^24).
__global__ __launch_bounds__(256) void dmc_fused(const float* __restrict__ g,
                                                 float* __restrict__ out) {
    const size_t lin = (size_t)blockIdx.x * 256 + threadIdx.x;
    if (lin >= NV) return;
    const int linI = (int)lin;
    const int k = linI % CN;
    const int t2 = linI / CN;
    const int j = t2 % CN;
    const int i = t2 / CN;

    // 8 corner values of padded cell: P[i+di][j+dj][k+dk] = grid[i-1+di][j-1+dj][k-1+dk]
    const float v000 = gpad(g, i - 1, j - 1, k - 1);
    const float v100 = gpad(g, i,     j - 1, k - 1);
    const float v010 = gpad(g, i - 1, j,     k - 1);
    const float v110 = gpad(g, i,     j,     k - 1);
    const float v001 = gpad(g, i - 1, j - 1, k);
    const float v101 = gpad(g, i,     j - 1, k);
    const float v011 = gpad(g, i - 1, j,     k);
    const float v111 = gpad(g, i,     j,     k);

    const bool s000 = v000 < 0.f, s100 = v100 < 0.f, s010 = v010 < 0.f, s110 = v110 < 0.f;
    const bool s001 = v001 < 0.f, s101 = v101 < 0.f, s011 = v011 < 0.f, s111 = v111 < 0.f;

    // ---- dual vertex: mean of iso-crossings on the 12 edges ----
    float sx = 0.f, sy = 0.f, sz = 0.f;
    int cnt = 0;
    auto acc = [&](float vA, float vB, bool sA, bool sB, int axis, float o1, float o2) {
        if (sA != sB) {
            const float t = -vA * __builtin_amdgcn_rcpf(vB - vA);
            if (axis == 0)      { sx += t;  sy += o1; sz += o2; }
            else if (axis == 1) { sx += o1; sy += t;  sz += o2; }
            else                { sx += o1; sy += o2; sz += t;  }
            cnt++;
        }
    };
    acc(v000, v100, s000, s100, 0, 0.f, 0.f);
    acc(v010, v110, s010, s110, 0, 1.f, 0.f);
    acc(v001, v101, s001, s101, 0, 0.f, 1.f);
    acc(v011, v111, s011, s111, 0, 1.f, 1.f);
    acc(v000, v010, s000, s010, 1, 0.f, 0.f);
    acc(v100, v110, s100, s110, 1, 1.f, 0.f);
    acc(v001, v011, s001, s011, 1, 0.f, 1.f);
    acc(v101, v111, s101, s111, 1, 1.f, 1.f);
    acc(v000, v001, s000, s001, 2, 0.f, 0.f);
    acc(v100, v101, s100, s101, 2, 1.f, 0.f);
    acc(v010, v011, s010, s011, 2, 0.f, 1.f);
    acc(v110, v111, s110, s111, 2, 1.f, 1.f);

    const float rc = __builtin_amdgcn_rcpf(fmaxf((float)cnt, 1.0f));
    const float inv191 = 1.0f / 191.0f;
    out[lin * 3 + 0] = ((float)i + sx * rc - 1.0f) * inv191;
    out[lin * 3 + 1] = ((float)j + sy * rc - 1.0f) * inv191;
    out[lin * 3 + 2] = ((float)k + sz * rc - 1.0f) * inv191;
    out[OFF_VMASK + lin] = (cnt > 0) ? 1.0f : 0.0f;

    const float flin = (float)linI;   // cell id of (i,j,k), exact (< 2^24)
    float4* const quads = (float4*)(out + OFF_QUADS);
    float* const qmask = out + OFF_QMASK;

    // ---- segment A: x-directed edge at (a=i, b=j+1, c=k+1); valid j<192 && k<192
    if (j < GN && k < GN) {
        const size_t r = ((size_t)i * GN + j) * GN + k;
        float4 q;
        q.x = flin;                 // cid(i, j,   k)
        q.y = flin + (float)CN;     // cid(i, j+1, k)
        q.z = flin + (float)(CN+1); // cid(i, j+1, k+1)
        q.w = flin + 1.0f;          // cid(i, j,   k+1)
        quads[r] = q;
        qmask[r] = (s011 != s111) ? 1.0f : 0.0f;
    }
    // ---- segment B: y-directed edge at (a=i, b=j, c=k+1); valid i>=1 && k<192
    if (i >= 1 && k < GN) {
        const size_t r = QSEG + ((size_t)(i - 1) * CN + j) * GN + k;
        float4 q;
        q.x = flin - (float)CN2;        // cid(i-1, j, k)
        q.y = flin;                     // cid(i,   j, k)
        q.z = flin + 1.0f;              // cid(i,   j, k+1)
        q.w = flin - (float)(CN2 - 1);  // cid(i-1, j, k+1)
        quads[r] = q;
        qmask[r] = (s001 != s011) ? 1.0f : 0.0f;
    }
    // ---- segment C: z-directed edge at (a=i, b=j, c=k); valid i>=1 && j>=1
    if (i >= 1 && j >= 1) {
        const size_t r = 2 * QSEG + ((size_t)(i - 1) * GN + (j - 1)) * CN + k;
        float4 q;
        q.x = flin - (float)(CN2 + CN); // cid(i-1, j-1, k)
        q.y = flin - (float)CN;         // cid(i,   j-1, k)
        q.z = flin;                     // cid(i,   j,   k)
        q.w = flin - (float)CN2;        // cid(i-1, j,   k)
        quads[r] = q;
        qmask[r] = (s000 != s001) ? 1.0f : 0.0f;
    }
}

extern "C" void kernel_launch(void* const* d_in, const int* in_sizes, int n_in,
                              void* d_out, int out_size, void* d_ws, size_t ws_size,
                              hipStream_t stream) {
    const float* g = (const float*)d_in[0];
    float* out = (float*)d_out;
    const int nblocks = (int)((NV + 255) / 256);   // 28083
    dmc_fused<<<dim3(nblocks), dim3(256), 0, stream>>>(g, out);
}